// Round 3
// baseline (281.725 us; speedup 1.0000x reference)
//
#include <hip/hip_runtime.h>

#define NB 16
#define TT 6000
#define HH 256
#define CC 105
#define MIN_GAP_ 19
#define REF_GAP_ 9

using short8 = __attribute__((ext_vector_type(8))) short;
using f32x4  = __attribute__((ext_vector_type(4))) float;

static __device__ __forceinline__ short f2bf(float x) {
  unsigned u = __builtin_bit_cast(unsigned, x);
  unsigned r = (u + 0x7FFFu + ((u >> 16) & 1u)) >> 16;   // RNE
  return (short)r;
}

// ---- one-time W (channels 1..104) f32 -> bf16, zero-padded to 112 rows ----
__global__ __launch_bounds__(256) void wconv_kernel(
    const float* __restrict__ W, unsigned short* __restrict__ Wb) {
  const int idx = blockIdx.x * 256 + threadIdx.x;   // 0..28671 (112*256)
  const int c = idx >> 8, k = idx & 255;
  const float v = (c < CC - 1) ? W[(size_t)(c + 1) * HH + k] : 0.f;
  Wb[idx] = (unsigned short)f2bf(v);
}

// ---- MFMA GEMM: out1 = feat @ Wb^T (bf16, f32 acc); ch0 f32 on the side ----
__global__ __launch_bounds__(256) void gemm_mfma(
    const float* __restrict__ feat, const float* __restrict__ W,
    const float* __restrict__ bias, const unsigned short* __restrict__ Wb,
    float* __restrict__ out0, float* __restrict__ out1) {
  const int tid  = threadIdx.x;
  const int wv   = tid >> 6;        // wave 0..3
  const int lane = tid & 63;
  const int rl   = lane & 15;       // A-row within wave / B-col (channel)
  const int kg   = lane >> 4;       // 0..3 (k-group of 8)
  const int row  = blockIdx.x * 64 + wv * 16 + rl;

  f32x4 acc[7];
#pragma unroll
  for (int n = 0; n < 7; n++) acc[n] = (f32x4){0.f, 0.f, 0.f, 0.f};
  float c0 = 0.f;

  const float* frow = feat + (size_t)row * HH;

#pragma unroll 2
  for (int ks = 0; ks < 8; ks++) {
    const int kk = ks * 32 + kg * 8;
    const float4 a0 = *reinterpret_cast<const float4*>(frow + kk);
    const float4 a1 = *reinterpret_cast<const float4*>(frow + kk + 4);
    const float4 w0a = *reinterpret_cast<const float4*>(W + kk);
    const float4 w0b = *reinterpret_cast<const float4*>(W + kk + 4);
    c0 = fmaf(a0.x, w0a.x, c0); c0 = fmaf(a0.y, w0a.y, c0);
    c0 = fmaf(a0.z, w0a.z, c0); c0 = fmaf(a0.w, w0a.w, c0);
    c0 = fmaf(a1.x, w0b.x, c0); c0 = fmaf(a1.y, w0b.y, c0);
    c0 = fmaf(a1.z, w0b.z, c0); c0 = fmaf(a1.w, w0b.w, c0);

    short8 av;
    av[0] = f2bf(a0.x); av[1] = f2bf(a0.y); av[2] = f2bf(a0.z); av[3] = f2bf(a0.w);
    av[4] = f2bf(a1.x); av[5] = f2bf(a1.y); av[6] = f2bf(a1.z); av[7] = f2bf(a1.w);

#pragma unroll
    for (int n = 0; n < 7; n++) {
      const short8 bv = *reinterpret_cast<const short8*>(
          Wb + ((size_t)(n * 16 + rl) << 8) + kk);
      acc[n] = __builtin_amdgcn_mfma_f32_16x16x32_bf16(av, bv, acc[n], 0, 0, 0);
    }
  }

  // ch0: reduce partial dot across the 4 k-group lanes sharing this row
  c0 += __shfl_xor(c0, 16);
  c0 += __shfl_xor(c0, 32);
  if (kg == 0) {
    const float v = c0 + bias[0];
    out0[row] = fminf(fmaxf(v, -16.f), 16.f);
  }

  // D layout: col = lane&15, row = (lane>>4)*4 + reg  [m89]
  const int rbase = blockIdx.x * 64 + wv * 16 + kg * 4;
#pragma unroll
  for (int n = 0; n < 7; n++) {
    const int c = n * 16 + rl;
    if (c < CC - 1) {
      const float bb = bias[c + 1];
#pragma unroll
      for (int r = 0; r < 4; r++)
        out1[(size_t)(rbase + r) * (CC - 1) + c] = acc[n][r] + bb;
    }
  }
}

// ---- phase: bitwise run detect + segmented-parallel merge + parallel p2 ----
#define NW 192   // 6144/32 bit-words

__global__ __launch_bounds__(512) void phase_kernel(
    const float* __restrict__ bd_logits,
    const int* __restrict__ word_bd,
    const float* __restrict__ non_padding,
    float* __restrict__ out2) {
  __shared__ __align__(16) float lbuf[TT];
  __shared__ unsigned char wbuf[TT];
  __shared__ int res[TT];
  __shared__ unsigned bdbits[NW];
  __shared__ int runIdx[3072];
  __shared__ int anch[3072];
  __shared__ int scn[512];
  __shared__ int L_sh, nruns_sh, nanch_sh;

  const int b = blockIdx.x;
  const int tid = threadIdx.x;
  const int lane = tid & 63;
  if (tid == 0) L_sh = 0;
  __syncthreads();

  // load + bd bitmask via ballot
  int cnt_np = 0;
#pragma unroll
  for (int k = 0; k < 12; k++) {
    const int j = k * 512 + tid;
    bool pred = false;
    if (j < TT) {
      const float l = bd_logits[(size_t)b * TT + j];
      lbuf[j] = l;
      pred = l > 0.f;                       // sigmoid(l) > 0.5
      wbuf[j] = (unsigned char)word_bd[(size_t)b * TT + j];
      res[j] = 0;
      cnt_np += (non_padding[(size_t)b * TT + j] != 0.f) ? 1 : 0;
    }
    const unsigned long long m = __ballot(pred);
    if (lane == 0) {
      const int w0 = (k * 512 + (tid & ~63)) >> 5;
      bdbits[w0]     = (unsigned)m;
      bdbits[w0 + 1] = (unsigned)(m >> 32);
    }
  }
#pragma unroll
  for (int off = 32; off; off >>= 1) cnt_np += __shfl_xor(cnt_np, off);
  if (lane == 0) atomicAdd(&L_sh, cnt_np);
  __syncthreads();

  // run-end detection per 32-bit word
  int cnt = 0;
  unsigned ends = 0;
  if (tid < NW) {
    const unsigned cur = bdbits[tid];
    const unsigned pb = tid ? (bdbits[tid - 1] >> 31) : 0u;
    ends = ((cur << 1) | pb) & ~cur;
    if (tid == 187) ends &= 0xFFFFu;        // e <= T-1
    cnt = __popc(ends);
  }
  scn[tid] = cnt;
  __syncthreads();
  for (int off = 1; off < 512; off <<= 1) {
    const int t = (tid >= off) ? scn[tid - off] : 0;
    __syncthreads();
    scn[tid] += t;
    __syncthreads();
  }
  if (tid == 511) nruns_sh = scn[511];
  int slot = scn[tid] - cnt;
  __syncthreads();

  // emit per-run argmax (forward, strict > = reference's first-max)
  if (ends) {
    unsigned m = ends;
    while (m) {
      const int bit = __builtin_ctz(m);
      m &= m - 1;
      const int e = tid * 32 + bit;
      const int eb = e - 1;
      int w = eb >> 5;
      const int bb = eb & 31;
      const unsigned z = bdbits[w] << (31 - bb);
      const unsigned nz = ~z;
      int run = nz ? __builtin_clz(nz) : 32;
      if (run == bb + 1) {
        while (w > 0) {
          w--;
          const unsigned nx = ~bdbits[w];
          const int t2 = nx ? __builtin_clz(nx) : 32;
          run += t2;
          if (t2 < 32) break;
        }
      }
      const int s = e - run;
      float mv = lbuf[s];
      int mi = s;
      for (int i = s + 1; i < e; i++) {
        const float v = lbuf[i];
        if (v > mv) { mv = v; mi = i; }
      }
      runIdx[slot++] = mi;
    }
  }
  __syncthreads();

  // anchors: i==0 or raw gap >= MIN_GAP (merges only move last down -> hard break)
  const int n = nruns_sh;
  int acnt = 0;
  unsigned aflags = 0;
  const int i0 = tid * 6;
#pragma unroll
  for (int q = 0; q < 6; q++) {
    const int i = i0 + q;
    if (i < n) {
      const bool f = (i == 0) || (runIdx[i] - runIdx[i - 1] >= MIN_GAP_);
      aflags |= (f ? 1u : 0u) << q;
      acnt += f ? 1 : 0;
    }
  }
  scn[tid] = acnt;
  __syncthreads();
  for (int off = 1; off < 512; off <<= 1) {
    const int t = (tid >= off) ? scn[tid - off] : 0;
    __syncthreads();
    scn[tid] += t;
    __syncthreads();
  }
  if (tid == 511) nanch_sh = scn[511];
  int aslot = scn[tid] - acnt;
  __syncthreads();
#pragma unroll
  for (int q = 0; q < 6; q++)
    if ((aflags >> q) & 1u) anch[aslot++] = i0 + q;
  __syncthreads();

  // segment-parallel merge chains (exact serial semantics within segment)
  const int na = nanch_sh;
  for (int a = tid; a < na; a += 512) {
    const int s0 = anch[a];
    const int s1 = (a + 1 < na) ? anch[a + 1] : n;
    int last = -1;
    int p0 = runIdx[s0];
    int p1 = (s0 + 1 < s1) ? runIdx[s0 + 1] : 0;
    for (int i = s0; i < s1; i++) {
      int bd = p0;
      p0 = p1;
      p1 = (i + 2 < s1) ? runIdx[i + 2] : 0;
      if (last > 0 && bd - last < MIN_GAP_) {
        const int sum = bd + last;
        const int h = sum >> 1;
        bd = (sum & 1) ? (h + (h & 1)) : h;   // round half to even
        res[last] = 0;
      }
      res[bd] = 1;
      last = bd;
    }
  }
  __syncthreads();

  // phase 2: parallel over word boundaries (>=25 apart, windows +-9 disjoint)
  for (int j = tid; j < TT; j += 512) {
    if (wbuf[j] != 1) continue;
    const int lo = (j - REF_GAP_ < 0) ? 0 : j - REF_GAP_;
    const int hi = (j + REF_GAP_ - 1 > TT - 1) ? TT - 1 : j + REF_GAP_ - 1;
    int seg = 0;
    for (int w = lo; w <= hi; w++) seg += res[w];
    if (seg == 0) {
      res[j] = 1;
    } else if (seg == 1) {
      if (res[j] != 1) {
        for (int w = lo; w <= hi; w++) res[w] = (int)wbuf[w];
      }
    } else {
      int zidx = -1;
      for (int k = 1; k <= REF_GAP_; k++) {
        const int li = (j - k < 0) ? 0 : j - k;
        const int ri = (j + k > TT - 1) ? TT - 1 : j + k;
        if (res[li] == 1 && wbuf[li] != 1) { zidx = li; break; }
        if (res[ri] == 1 && wbuf[ri] != 1) { zidx = ri; break; }
      }
      if (zidx >= 0) res[zidx] = 0;
      res[j] = 1;
    }
  }
  __syncthreads();

  const int L = L_sh;
  for (int t = tid; t < TT; t += 512)
    out2[(size_t)b * TT + t] = (t >= 1 && t < L - 1) ? (float)res[t] : 0.f;
}

extern "C" void kernel_launch(void* const* d_in, const int* in_sizes, int n_in,
                              void* d_out, int out_size, void* d_ws, size_t ws_size,
                              hipStream_t stream) {
  const float* feat        = (const float*)d_in[0];
  const int*   word_bd     = (const int*)d_in[1];
  const float* non_padding = (const float*)d_in[2];
  const float* W           = (const float*)d_in[3];
  const float* bias        = (const float*)d_in[4];

  float* out  = (float*)d_out;
  float* out0 = out;
  float* out1 = out + (size_t)NB * TT;
  float* out2 = out + (size_t)NB * TT + (size_t)NB * TT * (CC - 1);

  unsigned short* Wb = (unsigned short*)d_ws;   // 112*256 bf16 = 57344 B

  hipLaunchKernelGGL(wconv_kernel, dim3(112), dim3(256), 0, stream, W, Wb);
  hipLaunchKernelGGL(gemm_mfma, dim3((NB * TT) / 64), dim3(256), 0, stream,
                     feat, W, bias, Wb, out0, out1);
  hipLaunchKernelGGL(phase_kernel, dim3(NB), dim3(512), 0, stream,
                     out0, word_bd, non_padding, out2);
}

// Round 4
// 108.353 us; speedup vs baseline: 2.6001x; 2.6001x over previous
//
#include <hip/hip_runtime.h>

#define NB 16
#define TT 6000
#define HH 256
#define CC 105
#define MIN_GAP_ 19
#define REF_GAP_ 9

using short8 = __attribute__((ext_vector_type(8))) short;
using f32x4  = __attribute__((ext_vector_type(4))) float;

static __device__ __forceinline__ short f2bf(float x) {
  unsigned u = __builtin_bit_cast(unsigned, x);
  unsigned r = (u + 0x7FFFu + ((u >> 16) & 1u)) >> 16;   // RNE
  return (short)r;
}

// ---- one-time W (channels 1..104) f32 -> bf16, zero-padded to 112 rows ----
__global__ __launch_bounds__(256) void wconv_kernel(
    const float* __restrict__ W, unsigned short* __restrict__ Wb) {
  const int idx = blockIdx.x * 256 + threadIdx.x;   // 0..28671 (112*256)
  const int c = idx >> 8, k = idx & 255;
  const float v = (c < CC - 1) ? W[(size_t)(c + 1) * HH + k] : 0.f;
  Wb[idx] = (unsigned short)f2bf(v);
}

// ---- MFMA GEMM: out1 = feat @ Wb^T (bf16, f32 acc); ch0 f32 on the side ----
__global__ __launch_bounds__(256) void gemm_mfma(
    const float* __restrict__ feat, const float* __restrict__ W,
    const float* __restrict__ bias, const unsigned short* __restrict__ Wb,
    float* __restrict__ out0, float* __restrict__ out1) {
  const int tid  = threadIdx.x;
  const int wv   = tid >> 6;        // wave 0..3
  const int lane = tid & 63;
  const int rl   = lane & 15;       // A-row within wave / B-col (channel)
  const int kg   = lane >> 4;       // 0..3 (k-group of 8)
  const int row  = blockIdx.x * 64 + wv * 16 + rl;

  f32x4 acc[7];
#pragma unroll
  for (int n = 0; n < 7; n++) acc[n] = (f32x4){0.f, 0.f, 0.f, 0.f};
  float c0 = 0.f;

  const float* frow = feat + (size_t)row * HH;

#pragma unroll 2
  for (int ks = 0; ks < 8; ks++) {
    const int kk = ks * 32 + kg * 8;
    const float4 a0 = *reinterpret_cast<const float4*>(frow + kk);
    const float4 a1 = *reinterpret_cast<const float4*>(frow + kk + 4);
    const float4 w0a = *reinterpret_cast<const float4*>(W + kk);
    const float4 w0b = *reinterpret_cast<const float4*>(W + kk + 4);
    c0 = fmaf(a0.x, w0a.x, c0); c0 = fmaf(a0.y, w0a.y, c0);
    c0 = fmaf(a0.z, w0a.z, c0); c0 = fmaf(a0.w, w0a.w, c0);
    c0 = fmaf(a1.x, w0b.x, c0); c0 = fmaf(a1.y, w0b.y, c0);
    c0 = fmaf(a1.z, w0b.z, c0); c0 = fmaf(a1.w, w0b.w, c0);

    short8 av;
    av[0] = f2bf(a0.x); av[1] = f2bf(a0.y); av[2] = f2bf(a0.z); av[3] = f2bf(a0.w);
    av[4] = f2bf(a1.x); av[5] = f2bf(a1.y); av[6] = f2bf(a1.z); av[7] = f2bf(a1.w);

#pragma unroll
    for (int n = 0; n < 7; n++) {
      const short8 bv = *reinterpret_cast<const short8*>(
          Wb + ((size_t)(n * 16 + rl) << 8) + kk);
      acc[n] = __builtin_amdgcn_mfma_f32_16x16x32_bf16(av, bv, acc[n], 0, 0, 0);
    }
  }

  // ch0: reduce partial dot across the 4 k-group lanes sharing this row
  c0 += __shfl_xor(c0, 16);
  c0 += __shfl_xor(c0, 32);
  if (kg == 0) {
    const float v = c0 + bias[0];
    out0[row] = fminf(fmaxf(v, -16.f), 16.f);
  }

  // D layout: col = lane&15, row = (lane>>4)*4 + reg  [m89]
  const int rbase = blockIdx.x * 64 + wv * 16 + kg * 4;
#pragma unroll
  for (int n = 0; n < 7; n++) {
    const int c = n * 16 + rl;
    if (c < CC - 1) {
      const float bb = bias[c + 1];
#pragma unroll
      for (int r = 0; r < 4; r++)
        out1[(size_t)(rbase + r) * (CC - 1) + c] = acc[n][r] + bb;
    }
  }
}

// ---- phase: bitwise run detect + chunk-speculative merge + parallel p2 ----
#define NW 192        // 6144/32 bit-words
#define NW_LAST 187   // word containing T-1
#define CHUNK 32
#define NCLS 19       // incoming-last classes: p0-18..p0-1 (18) + no-merge (1)
#define MAXRUNS 3072
#define MAXCH 96      // MAXRUNS/CHUNK

__global__ __launch_bounds__(512) void phase_kernel(
    const float* __restrict__ bd_logits,
    const int* __restrict__ word_bd,
    const float* __restrict__ non_padding,
    float* __restrict__ out2) {
  __shared__ __align__(16) float lbuf[TT];
  __shared__ unsigned char wbuf[TT];
  __shared__ int res[TT];
  __shared__ unsigned bdbits[NW];
  __shared__ int runIdx[MAXRUNS];
  __shared__ int outLast[MAXCH][NCLS + 1];
  __shared__ int chP0[MAXCH];
  __shared__ int inL[MAXCH + 1];
  __shared__ int wsum[8];
  __shared__ int wbase[8];
  __shared__ int L_sh, nruns_sh;

  const int b = blockIdx.x;
  const int tid = threadIdx.x;
  const int lane = tid & 63;
  const int wid = tid >> 6;
  if (tid == 0) L_sh = 0;
  __syncthreads();

  // ---- load + bd bitmask via ballot ----
  int cnt_np = 0;
#pragma unroll
  for (int k = 0; k < 12; k++) {
    const int j = k * 512 + tid;
    bool pred = false;
    if (j < TT) {
      const float l = bd_logits[(size_t)b * TT + j];
      lbuf[j] = l;
      pred = l > 0.f;                       // sigmoid(l) > 0.5
      wbuf[j] = (unsigned char)word_bd[(size_t)b * TT + j];
      res[j] = 0;
      cnt_np += (non_padding[(size_t)b * TT + j] != 0.f) ? 1 : 0;
    }
    const unsigned long long m = __ballot(pred);
    if (lane == 0) {
      const int w0 = (k * 512 + (tid & ~63)) >> 5;
      bdbits[w0]     = (unsigned)m;
      bdbits[w0 + 1] = (unsigned)(m >> 32);
    }
  }
#pragma unroll
  for (int off = 32; off; off >>= 1) cnt_np += __shfl_xor(cnt_np, off);
  if (lane == 0) atomicAdd(&L_sh, cnt_np);
  __syncthreads();

  // ---- run-end detection per 32-bit word ----
  int cnt = 0;
  unsigned ends = 0;
  if (tid < NW) {
    const unsigned cur = bdbits[tid];
    const unsigned pb = tid ? (bdbits[tid - 1] >> 31) : 0u;
    ends = ((cur << 1) | pb) & ~cur;
    if (tid == NW_LAST) ends &= 0xFFFFu;    // e <= T-1
    cnt = __popc(ends);
  }
  // shfl wave-scan + tiny cross-wave scan
  int v = cnt;
#pragma unroll
  for (int off = 1; off < 64; off <<= 1) {
    const int t = __shfl_up(v, off);
    if (lane >= off) v += t;
  }
  if (lane == 63) wsum[wid] = v;
  __syncthreads();
  if (tid == 0) {
    int s = 0;
#pragma unroll
    for (int w = 0; w < 8; w++) { wbase[w] = s; s += wsum[w]; }
    nruns_sh = s;
  }
  __syncthreads();
  int slot = wbase[wid] + v - cnt;

  // ---- emit per-run argmax (forward, strict > = first-max) ----
  if (ends) {
    unsigned m = ends;
    while (m) {
      const int bit = __builtin_ctz(m);
      m &= m - 1;
      const int e = tid * 32 + bit;
      const int eb = e - 1;
      int w = eb >> 5;
      const int bb = eb & 31;
      const unsigned z = bdbits[w] << (31 - bb);
      const unsigned nz = ~z;
      int run = nz ? __builtin_clz(nz) : 32;
      if (run == bb + 1) {
        while (w > 0) {
          w--;
          const unsigned nx = ~bdbits[w];
          const int t2 = nx ? __builtin_clz(nx) : 32;
          run += t2;
          if (t2 < 32) break;
        }
      }
      const int s = e - run;
      float mv = lbuf[s];
      int mi = s;
      for (int i = s + 1; i < e; i++) {
        const float val = lbuf[i];
        if (val > mv) { mv = val; mi = i; }
      }
      runIdx[slot++] = mi;
    }
  }
  __syncthreads();

  // ---- speculative chunk sims: outLast[ch][cls] for 19 incoming classes ----
  const int n = nruns_sh;
  const int nch = (n + CHUNK - 1) / CHUNK;
  for (int f = tid; f < nch * NCLS; f += 512) {
    const int ch = f / NCLS;
    const int cls = f - ch * NCLS;
    const int s = ch * CHUNK;
    const int e = (s + CHUNK < n) ? s + CHUNK : n;
    const int p0 = runIdx[s];
    if (cls == NCLS - 1) chP0[ch] = p0;
    int last = (cls < 18) ? (p0 - 18 + cls) : -1;
    for (int i = s; i < e; i++) {
      int bd = runIdx[i];
      if (last > 0 && bd - last < MIN_GAP_) {
        const int sum = bd + last;
        const int h = sum >> 1;
        bd = (sum & 1) ? (h + (h & 1)) : h;   // round half to even
      }
      last = bd;
    }
    outLast[ch][cls] = last;
  }
  __syncthreads();

  // ---- stitch: serial over chunks, O(1) per chunk via shfl-select ----
  if (wid == 0) {
    int q = -1;
    int row = (lane < NCLS && nch > 0) ? outLast[0][lane] : -1;
    for (int ch = 0; ch < nch; ch++) {
      const int rown = (lane < NCLS && ch + 1 < nch) ? outLast[ch + 1][lane] : -1;
      const int p0 = chP0[ch];
      const int cls = (q > 0 && p0 - q < MIN_GAP_) ? (q - (p0 - 18)) : (NCLS - 1);
      if (lane == 0) inL[ch] = q;
      q = __shfl(row, cls);
      row = rown;
    }
    if (lane == 0) inL[nch] = q;
  }
  __syncthreads();

  // ---- replay: one thread per chunk; disjoint write ownership [qin, qout) ----
  for (int ch = tid; ch < nch; ch += 512) {
    const int s = ch * CHUNK;
    const int e = (s + CHUNK < n) ? s + CHUNK : n;
    const int qin = inL[ch];
    const int qout = inL[ch + 1];
    if (qin >= 0 && qin != qout) res[qin] = 1;   // previous chunk's deferred set
    int last = qin;
    for (int i = s; i < e; i++) {
      int bd = runIdx[i];
      if (last > 0 && bd - last < MIN_GAP_) {
        const int sum = bd + last;
        const int h = sum >> 1;
        bd = (sum & 1) ? (h + (h & 1)) : h;
        if (last != qout) res[last] = 0;
      }
      if (bd != qout) res[bd] = 1;
      last = bd;
    }
  }
  if (tid == 0 && n > 0) res[inL[nch]] = 1;      // final boundary always set
  __syncthreads();

  // ---- phase 2: parallel over word boundaries (>=25 apart, +-9 windows) ----
  for (int j = tid; j < TT; j += 512) {
    if (wbuf[j] != 1) continue;
    const int lo = (j - REF_GAP_ < 0) ? 0 : j - REF_GAP_;
    const int hi = (j + REF_GAP_ - 1 > TT - 1) ? TT - 1 : j + REF_GAP_ - 1;
    int seg = 0;
    for (int w = lo; w <= hi; w++) seg += res[w];
    if (seg == 0) {
      res[j] = 1;
    } else if (seg == 1) {
      if (res[j] != 1) {
        for (int w = lo; w <= hi; w++) res[w] = (int)wbuf[w];
      }
    } else {
      int zidx = -1;
      for (int k = 1; k <= REF_GAP_; k++) {
        const int li = (j - k < 0) ? 0 : j - k;
        const int ri = (j + k > TT - 1) ? TT - 1 : j + k;
        if (res[li] == 1 && wbuf[li] != 1) { zidx = li; break; }
        if (res[ri] == 1 && wbuf[ri] != 1) { zidx = ri; break; }
      }
      if (zidx >= 0) res[zidx] = 0;
      res[j] = 1;
    }
  }
  __syncthreads();

  const int L = L_sh;
  for (int t = tid; t < TT; t += 512)
    out2[(size_t)b * TT + t] = (t >= 1 && t < L - 1) ? (float)res[t] : 0.f;
}

extern "C" void kernel_launch(void* const* d_in, const int* in_sizes, int n_in,
                              void* d_out, int out_size, void* d_ws, size_t ws_size,
                              hipStream_t stream) {
  const float* feat        = (const float*)d_in[0];
  const int*   word_bd     = (const int*)d_in[1];
  const float* non_padding = (const float*)d_in[2];
  const float* W           = (const float*)d_in[3];
  const float* bias        = (const float*)d_in[4];

  float* out  = (float*)d_out;
  float* out0 = out;
  float* out1 = out + (size_t)NB * TT;
  float* out2 = out + (size_t)NB * TT + (size_t)NB * TT * (CC - 1);

  unsigned short* Wb = (unsigned short*)d_ws;   // 112*256 bf16 = 57344 B

  hipLaunchKernelGGL(wconv_kernel, dim3(112), dim3(256), 0, stream, W, Wb);
  hipLaunchKernelGGL(gemm_mfma, dim3((NB * TT) / 64), dim3(256), 0, stream,
                     feat, W, bias, Wb, out0, out1);
  hipLaunchKernelGGL(phase_kernel, dim3(NB), dim3(512), 0, stream,
                     out0, word_bd, non_padding, out2);
}

// Round 5
// 98.867 us; speedup vs baseline: 2.8495x; 1.0960x over previous
//
#include <hip/hip_runtime.h>

#define NB 16
#define TT 6000
#define HH 256
#define CC 105
#define MIN_GAP_ 19
#define REF_GAP_ 9

using short8 = __attribute__((ext_vector_type(8))) short;
using f32x4  = __attribute__((ext_vector_type(4))) float;

static __device__ __forceinline__ short f2bf(float x) {
  unsigned u = __builtin_bit_cast(unsigned, x);
  unsigned r = (u + 0x7FFFu + ((u >> 16) & 1u)) >> 16;   // RNE
  return (short)r;
}

// ---- one-time W (channels 1..104) f32 -> bf16, zero-padded to 112 rows ----
__global__ __launch_bounds__(256) void wconv_kernel(
    const float* __restrict__ W, unsigned short* __restrict__ Wb) {
  const int idx = blockIdx.x * 256 + threadIdx.x;   // 0..28671 (112*256)
  const int c = idx >> 8, k = idx & 255;
  const float v = (c < CC - 1) ? W[(size_t)(c + 1) * HH + k] : 0.f;
  Wb[idx] = (unsigned short)f2bf(v);
}

// ---- MFMA GEMM, deep-MLP version: issue all 16 A-loads, then convert,
// ---- then 56 MFMAs with B from L2. ch0 f32 dot on the side (bit-identical
// ---- FMA order to previous round). ----
__global__ __launch_bounds__(256) void gemm_mfma(
    const float* __restrict__ feat, const float* __restrict__ W,
    const float* __restrict__ bias, const unsigned short* __restrict__ Wb,
    float* __restrict__ out0, float* __restrict__ out1) {
  const int tid  = threadIdx.x;
  const int wv   = tid >> 6;        // wave 0..3
  const int lane = tid & 63;
  const int rl   = lane & 15;       // A-row within wave / B-col (channel)
  const int kg   = lane >> 4;       // 0..3 (k-group of 8)
  const int row  = blockIdx.x * 64 + wv * 16 + rl;
  const float* frow = feat + (size_t)row * HH;

  // 1) issue all 16 independent A loads (256B/lane in flight)
  float4 a0[8], a1[8];
#pragma unroll
  for (int ks = 0; ks < 8; ks++) {
    const int kk = ks * 32 + kg * 8;
    a0[ks] = *reinterpret_cast<const float4*>(frow + kk);
    a1[ks] = *reinterpret_cast<const float4*>(frow + kk + 4);
  }

  // 2) convert to bf16 + ch0 f32 dot (same FMA order as before)
  float c0 = 0.f;
  short8 av[8];
#pragma unroll
  for (int ks = 0; ks < 8; ks++) {
    const int kk = ks * 32 + kg * 8;
    const float4 w0a = *reinterpret_cast<const float4*>(W + kk);
    const float4 w0b = *reinterpret_cast<const float4*>(W + kk + 4);
    c0 = fmaf(a0[ks].x, w0a.x, c0); c0 = fmaf(a0[ks].y, w0a.y, c0);
    c0 = fmaf(a0[ks].z, w0a.z, c0); c0 = fmaf(a0[ks].w, w0a.w, c0);
    c0 = fmaf(a1[ks].x, w0b.x, c0); c0 = fmaf(a1[ks].y, w0b.y, c0);
    c0 = fmaf(a1[ks].z, w0b.z, c0); c0 = fmaf(a1[ks].w, w0b.w, c0);

    short8 t;
    t[0] = f2bf(a0[ks].x); t[1] = f2bf(a0[ks].y);
    t[2] = f2bf(a0[ks].z); t[3] = f2bf(a0[ks].w);
    t[4] = f2bf(a1[ks].x); t[5] = f2bf(a1[ks].y);
    t[6] = f2bf(a1[ks].z); t[7] = f2bf(a1[ks].w);
    av[ks] = t;
  }

  // 3) MFMA sweep: 7 channel-groups x 8 k-steps, B loads batched per ks
  f32x4 acc[7];
#pragma unroll
  for (int n = 0; n < 7; n++) acc[n] = (f32x4){0.f, 0.f, 0.f, 0.f};

#pragma unroll
  for (int ks = 0; ks < 8; ks++) {
    const int kk = ks * 32 + kg * 8;
    short8 bv[7];
#pragma unroll
    for (int n = 0; n < 7; n++)
      bv[n] = *reinterpret_cast<const short8*>(
          Wb + ((size_t)(n * 16 + rl) << 8) + kk);
#pragma unroll
    for (int n = 0; n < 7; n++)
      acc[n] = __builtin_amdgcn_mfma_f32_16x16x32_bf16(av[ks], bv[n], acc[n], 0, 0, 0);
  }

  // ch0: reduce partial dot across the 4 k-group lanes sharing this row
  c0 += __shfl_xor(c0, 16);
  c0 += __shfl_xor(c0, 32);
  if (kg == 0) {
    const float v = c0 + bias[0];
    out0[row] = fminf(fmaxf(v, -16.f), 16.f);
  }

  // D layout: col = lane&15, row = (lane>>4)*4 + reg  [m89]
  const int rbase = blockIdx.x * 64 + wv * 16 + kg * 4;
#pragma unroll
  for (int n = 0; n < 7; n++) {
    const int c = n * 16 + rl;
    if (c < CC - 1) {
      const float bb = bias[c + 1];
#pragma unroll
      for (int r = 0; r < 4; r++)
        out1[(size_t)(rbase + r) * (CC - 1) + c] = acc[n][r] + bb;
    }
  }
}

// ---- phase: bitwise run detect + chunk-speculative merge + parallel p2 ----
#define NW 192        // 6144/32 bit-words
#define NW_LAST 187   // word containing T-1
#define CHUNK 32
#define NCLS 19       // incoming-last classes: p0-18..p0-1 (18) + no-merge (1)
#define MAXRUNS 3072
#define MAXCH 96      // MAXRUNS/CHUNK

__global__ __launch_bounds__(512) void phase_kernel(
    const float* __restrict__ bd_logits,
    const int* __restrict__ word_bd,
    const float* __restrict__ non_padding,
    float* __restrict__ out2) {
  __shared__ __align__(16) float lbuf[TT];
  __shared__ unsigned char wbuf[TT];
  __shared__ int res[TT];
  __shared__ unsigned bdbits[NW];
  __shared__ int runIdx[MAXRUNS];
  __shared__ int outLast[MAXCH][NCLS + 1];
  __shared__ int chP0[MAXCH];
  __shared__ int inL[MAXCH + 1];
  __shared__ int wsum[8];
  __shared__ int wbase[8];
  __shared__ int L_sh, nruns_sh;

  const int b = blockIdx.x;
  const int tid = threadIdx.x;
  const int lane = tid & 63;
  const int wid = tid >> 6;
  if (tid == 0) L_sh = 0;
  __syncthreads();

  // ---- load + bd bitmask via ballot ----
  int cnt_np = 0;
#pragma unroll
  for (int k = 0; k < 12; k++) {
    const int j = k * 512 + tid;
    bool pred = false;
    if (j < TT) {
      const float l = bd_logits[(size_t)b * TT + j];
      lbuf[j] = l;
      pred = l > 0.f;                       // sigmoid(l) > 0.5
      wbuf[j] = (unsigned char)word_bd[(size_t)b * TT + j];
      res[j] = 0;
      cnt_np += (non_padding[(size_t)b * TT + j] != 0.f) ? 1 : 0;
    }
    const unsigned long long m = __ballot(pred);
    if (lane == 0) {
      const int w0 = (k * 512 + (tid & ~63)) >> 5;
      bdbits[w0]     = (unsigned)m;
      bdbits[w0 + 1] = (unsigned)(m >> 32);
    }
  }
#pragma unroll
  for (int off = 32; off; off >>= 1) cnt_np += __shfl_xor(cnt_np, off);
  if (lane == 0) atomicAdd(&L_sh, cnt_np);
  __syncthreads();

  // ---- run-end detection per 32-bit word ----
  int cnt = 0;
  unsigned ends = 0;
  if (tid < NW) {
    const unsigned cur = bdbits[tid];
    const unsigned pb = tid ? (bdbits[tid - 1] >> 31) : 0u;
    ends = ((cur << 1) | pb) & ~cur;
    if (tid == NW_LAST) ends &= 0xFFFFu;    // e <= T-1
    cnt = __popc(ends);
  }
  // shfl wave-scan + tiny cross-wave scan
  int v = cnt;
#pragma unroll
  for (int off = 1; off < 64; off <<= 1) {
    const int t = __shfl_up(v, off);
    if (lane >= off) v += t;
  }
  if (lane == 63) wsum[wid] = v;
  __syncthreads();
  if (tid == 0) {
    int s = 0;
#pragma unroll
    for (int w = 0; w < 8; w++) { wbase[w] = s; s += wsum[w]; }
    nruns_sh = s;
  }
  __syncthreads();
  int slot = wbase[wid] + v - cnt;

  // ---- emit per-run argmax (forward, strict > = first-max) ----
  if (ends) {
    unsigned m = ends;
    while (m) {
      const int bit = __builtin_ctz(m);
      m &= m - 1;
      const int e = tid * 32 + bit;
      const int eb = e - 1;
      int w = eb >> 5;
      const int bb = eb & 31;
      const unsigned z = bdbits[w] << (31 - bb);
      const unsigned nz = ~z;
      int run = nz ? __builtin_clz(nz) : 32;
      if (run == bb + 1) {
        while (w > 0) {
          w--;
          const unsigned nx = ~bdbits[w];
          const int t2 = nx ? __builtin_clz(nx) : 32;
          run += t2;
          if (t2 < 32) break;
        }
      }
      const int s = e - run;
      float mv = lbuf[s];
      int mi = s;
      for (int i = s + 1; i < e; i++) {
        const float val = lbuf[i];
        if (val > mv) { mv = val; mi = i; }
      }
      runIdx[slot++] = mi;
    }
  }
  __syncthreads();

  // ---- speculative chunk sims: outLast[ch][cls] for 19 incoming classes ----
  const int n = nruns_sh;
  const int nch = (n + CHUNK - 1) / CHUNK;
  for (int f = tid; f < nch * NCLS; f += 512) {
    const int ch = f / NCLS;
    const int cls = f - ch * NCLS;
    const int s = ch * CHUNK;
    const int e = (s + CHUNK < n) ? s + CHUNK : n;
    const int p0 = runIdx[s];
    if (cls == NCLS - 1) chP0[ch] = p0;
    int last = (cls < 18) ? (p0 - 18 + cls) : -1;
    for (int i = s; i < e; i++) {
      int bd = runIdx[i];
      if (last > 0 && bd - last < MIN_GAP_) {
        const int sum = bd + last;
        const int h = sum >> 1;
        bd = (sum & 1) ? (h + (h & 1)) : h;   // round half to even
      }
      last = bd;
    }
    outLast[ch][cls] = last;
  }
  __syncthreads();

  // ---- stitch: serial over chunks, O(1) per chunk via shfl-select ----
  if (wid == 0) {
    int q = -1;
    int row = (lane < NCLS && nch > 0) ? outLast[0][lane] : -1;
    for (int ch = 0; ch < nch; ch++) {
      const int rown = (lane < NCLS && ch + 1 < nch) ? outLast[ch + 1][lane] : -1;
      const int p0 = chP0[ch];
      const int cls = (q > 0 && p0 - q < MIN_GAP_) ? (q - (p0 - 18)) : (NCLS - 1);
      if (lane == 0) inL[ch] = q;
      q = __shfl(row, cls);
      row = rown;
    }
    if (lane == 0) inL[nch] = q;
  }
  __syncthreads();

  // ---- replay: one thread per chunk; disjoint write ownership [qin, qout) ----
  for (int ch = tid; ch < nch; ch += 512) {
    const int s = ch * CHUNK;
    const int e = (s + CHUNK < n) ? s + CHUNK : n;
    const int qin = inL[ch];
    const int qout = inL[ch + 1];
    if (qin >= 0 && qin != qout) res[qin] = 1;   // previous chunk's deferred set
    int last = qin;
    for (int i = s; i < e; i++) {
      int bd = runIdx[i];
      if (last > 0 && bd - last < MIN_GAP_) {
        const int sum = bd + last;
        const int h = sum >> 1;
        bd = (sum & 1) ? (h + (h & 1)) : h;
        if (last != qout) res[last] = 0;
      }
      if (bd != qout) res[bd] = 1;
      last = bd;
    }
  }
  if (tid == 0 && n > 0) res[inL[nch]] = 1;      // final boundary always set
  __syncthreads();

  // ---- phase 2: parallel over word boundaries (>=25 apart, +-9 windows) ----
  for (int j = tid; j < TT; j += 512) {
    if (wbuf[j] != 1) continue;
    const int lo = (j - REF_GAP_ < 0) ? 0 : j - REF_GAP_;
    const int hi = (j + REF_GAP_ - 1 > TT - 1) ? TT - 1 : j + REF_GAP_ - 1;
    int seg = 0;
    for (int w = lo; w <= hi; w++) seg += res[w];
    if (seg == 0) {
      res[j] = 1;
    } else if (seg == 1) {
      if (res[j] != 1) {
        for (int w = lo; w <= hi; w++) res[w] = (int)wbuf[w];
      }
    } else {
      int zidx = -1;
      for (int k = 1; k <= REF_GAP_; k++) {
        const int li = (j - k < 0) ? 0 : j - k;
        const int ri = (j + k > TT - 1) ? TT - 1 : j + k;
        if (res[li] == 1 && wbuf[li] != 1) { zidx = li; break; }
        if (res[ri] == 1 && wbuf[ri] != 1) { zidx = ri; break; }
      }
      if (zidx >= 0) res[zidx] = 0;
      res[j] = 1;
    }
  }
  __syncthreads();

  const int L = L_sh;
  for (int t = tid; t < TT; t += 512)
    out2[(size_t)b * TT + t] = (t >= 1 && t < L - 1) ? (float)res[t] : 0.f;
}

extern "C" void kernel_launch(void* const* d_in, const int* in_sizes, int n_in,
                              void* d_out, int out_size, void* d_ws, size_t ws_size,
                              hipStream_t stream) {
  const float* feat        = (const float*)d_in[0];
  const int*   word_bd     = (const int*)d_in[1];
  const float* non_padding = (const float*)d_in[2];
  const float* W           = (const float*)d_in[3];
  const float* bias        = (const float*)d_in[4];

  float* out  = (float*)d_out;
  float* out0 = out;
  float* out1 = out + (size_t)NB * TT;
  float* out2 = out + (size_t)NB * TT + (size_t)NB * TT * (CC - 1);

  unsigned short* Wb = (unsigned short*)d_ws;   // 112*256 bf16 = 57344 B

  hipLaunchKernelGGL(wconv_kernel, dim3(112), dim3(256), 0, stream, W, Wb);
  hipLaunchKernelGGL(gemm_mfma, dim3((NB * TT) / 64), dim3(256), 0, stream,
                     feat, W, bias, Wb, out0, out1);
  hipLaunchKernelGGL(phase_kernel, dim3(NB), dim3(512), 0, stream,
                     out0, word_bd, non_padding, out2);
}